// Round 7
// baseline (432.007 us; speedup 1.0000x reference)
//
#include <hip/hip_runtime.h>
#include <hip/hip_bf16.h>
#include <math.h>

using bf16 = __hip_bfloat16;
using frag8 = __attribute__((ext_vector_type(8))) short;
using f32x4 = __attribute__((ext_vector_type(4))) float;

#define LEAKY 0.2f
#define BN_EPS 1e-5f
#define NEGBIG -1e30f

__device__ __forceinline__ float lrelu(float z){ return z > 0.f ? z : LEAKY * z; }
__device__ __forceinline__ float bflo(unsigned u){ return __uint_as_float(u << 16); }
__device__ __forceinline__ float bfhi(unsigned u){ return __uint_as_float(u & 0xffff0000u); }
// pack two floats into bf16 pair (RNE)
__device__ __forceinline__ unsigned pk(float a, float b){
  unsigned ua = __float_as_uint(a), ub = __float_as_uint(b);
  ua += 0x7fffu + ((ua >> 16) & 1u);
  ub += 0x7fffu + ((ub >> 16) & 1u);
  return (ua >> 16) | (ub & 0xffff0000u);
}
// dtype-adaptive load: isbf=1 -> bf16, else fp32
__device__ __forceinline__ float ldf(const void* p, size_t i, int isbf){
  if (isbf) return (float)((const bf16*)p)[i];
  return ((const float*)p)[i];
}

union U4F8 { uint4 u; frag8 f; };

__device__ __forceinline__ frag8 load_a_pairs(const unsigned* __restrict__ X2, int node, int k0){
  U4F8 v; v.u = *((const uint4*)(X2 + (size_t)node*64 + (k0 >> 1))); return v.f;
}
__device__ __forceinline__ frag8 load_a_f32(const float* __restrict__ X, int node, int k0){
  float4 q0 = *((const float4*)(X + (size_t)node*128 + k0));
  float4 q1 = *((const float4*)(X + (size_t)node*128 + k0 + 4));
  U4F8 v; v.u = make_uint4(pk(q0.x,q0.y), pk(q0.z,q0.w), pk(q1.x,q1.y), pk(q1.z,q1.w));
  return v.f;
}

// ------------- head init (-1) + total=0 + fused input-dtype detector ----------
__global__ void init_detect(int* head, const unsigned short* __restrict__ w1bits,
                            int* flag, int* total, int n){
  int g = blockIdx.x*256 + threadIdx.x;
  if (g < n) head[g] = -1;
  if (g == 0) *total = 0;
  if (blockIdx.x == 0){
    __shared__ int cntr;
    if (threadIdx.x == 0) cntr = 0;
    __syncthreads();
    unsigned u = w1bits[threadIdx.x * 2];
    int e = (u >> 7) & 0xff;
    atomicAdd(&cntr, (e >= 64 && e <= 140) ? 1 : 0);
    __syncthreads();
    if (threadIdx.x == 0) *flag = (cntr >= 160) ? 1 : 0;
  }
}

// ------------- chain build: next[e] = atomicExch(&head[dst[e]], e) ------------
__global__ void chain_build(const int* __restrict__ dst, int* head, int* next,
                            int e, int n){
  int g = blockIdx.x*256 + threadIdx.x;
  if (g < e){
    int d = dst[g];
    next[g] = ((unsigned)d < (unsigned)n) ? atomicExch(&head[d], g) : -1;
  }
}

// ------------- fused chain-walk degree count + block scan -> start ------------
__global__ void csr_scan_walk(const int* __restrict__ head, const int* __restrict__ next,
                              int* cnt, int* start, int* total, int n){
  __shared__ int s[256];
  __shared__ int base_s;
  int t = threadIdx.x;
  int g = blockIdx.x*256 + t;
  int v = 0;
  if (g < n){
    for (int e = head[g]; e != -1; e = next[e]) ++v;
    cnt[g] = v;
  }
  s[t] = v;
  __syncthreads();
  for (int off = 1; off < 256; off <<= 1){
    int x = (t >= off) ? s[t-off] : 0;
    __syncthreads();
    s[t] += x;
    __syncthreads();
  }
  if (t == 255) base_s = atomicAdd(total, s[255]);
  __syncthreads();
  if (g < n) start[g] = base_s + s[t] - v;
}

// ------------- per-node chain walk: sequential col + rowid fill ---------------
__global__ void chain_fill(const int* __restrict__ head, const int* __restrict__ next,
                           const int* __restrict__ src, const int* __restrict__ start,
                           int* col, int* rowid, int n){
  int g = blockIdx.x*256 + threadIdx.x;
  if (g >= n) return;
  int p = start[g];
  for (int e = head[g]; e != -1; e = next[e]){
    int s = src[e];
    if ((unsigned)s >= (unsigned)n) s = 0;   // clamp once here, not per-layer
    col[p] = s; rowid[p] = g; ++p;
  }
}

// ------------- edge-weight precompute (CSR-slot-parallel) ---------------------
__global__ void wgt4(const int* __restrict__ col, const int* __restrict__ rowid,
                     const float4* __restrict__ AL4, const float4* __restrict__ AD4,
                     float4* __restrict__ W4, int ecnt, int n){
  int p = blockIdx.x*256 + threadIdx.x;
  if (p >= ecnt) return;
  int s = col[p];   if ((unsigned)s >= (unsigned)n) s = 0;
  int d = rowid[p]; if ((unsigned)d >= (unsigned)n) d = 0;
  float4 a = AL4[s], b = AD4[d];
  float4 w;
  w.x = __expf(lrelu(a.x + b.x));
  w.y = __expf(lrelu(a.y + b.y));
  w.z = __expf(lrelu(a.z + b.z));
  w.w = __expf(lrelu(a.w + b.w));
  W4[p] = w;
}
__global__ void wgt1(const int* __restrict__ col, const int* __restrict__ rowid,
                     const float* __restrict__ AL, const float* __restrict__ AD,
                     float* __restrict__ W1, int ecnt, int n){
  int p = blockIdx.x*256 + threadIdx.x;
  if (p >= ecnt) return;
  int s = col[p];   if ((unsigned)s >= (unsigned)n) s = 0;
  int d = rowid[p]; if ((unsigned)d >= (unsigned)n) d = 0;
  W1[p] = __expf(lrelu(AL[s] + AD[d]));
}

// ---------------- MFMA GEMM 128x128 + fused al (layers 1,2) --------------------
__global__ __launch_bounds__(256) void gemm_al_mfma(
    const void* __restrict__ X, int xkind,
    const void* __restrict__ W, const void* __restrict__ Wsrc, const void* __restrict__ Wdst,
    const int* __restrict__ flagp,
    unsigned* __restrict__ H2, float* __restrict__ AL, float* __restrict__ AD,
    int n, int ntiles)
{
  __shared__ unsigned short WT[128*136];
  const int isbf = *flagp;
  const int t = threadIdx.x;
  if (isbf){
    const unsigned short* W16 = (const unsigned short*)W;
    for (int idx = t; idx < 16384; idx += 256){
      int k = idx >> 7, nn = idx & 127;
      WT[nn*136 + k] = W16[idx];
    }
  } else {
    const float* Wf = (const float*)W;
    for (int idx = t; idx < 16384; idx += 256){
      int k = idx >> 7, nn = idx & 127;
      WT[nn*136 + k] = (unsigned short)(pk(Wf[idx], 0.f) & 0xffffu);
    }
  }
  __syncthreads();
  const int w = t >> 6;
  const int lane = t & 63;
  const int m = lane & 15, quad = lane >> 4;

  frag8 bf[4][2];
  #pragma unroll
  for (int s = 0; s < 4; ++s)
    #pragma unroll
    for (int ct = 0; ct < 2; ++ct){
      int colc = w*32 + ct*16 + m;
      int k0 = s*32 + quad*8;
      U4F8 v; v.u = *((const uint4*)&WT[colc*136 + k0]);
      bf[s][ct] = v.f;
    }
  float avv[2], dvv[2];
  #pragma unroll
  for (int ct = 0; ct < 2; ++ct){
    int colc = w*32 + ct*16 + m;
    avv[ct] = ldf(Wsrc, colc, isbf);
    dvv[ct] = ldf(Wdst, colc, isbf);
  }
  const bool pairs = (xkind == 1) || isbf;

  for (int tile = blockIdx.x; tile < ntiles; tile += gridDim.x){
    const int mb = tile*16;
    int nodeA = mb + m; if (nodeA >= n) nodeA = n - 1;
    frag8 af[4];
    #pragma unroll
    for (int s = 0; s < 4; ++s){
      int k0 = s*32 + quad*8;
      af[s] = pairs ? load_a_pairs((const unsigned*)X, nodeA, k0)
                    : load_a_f32((const float*)X, nodeA, k0);
    }
    f32x4 acc0 = {0.f,0.f,0.f,0.f}, acc1 = {0.f,0.f,0.f,0.f};
    #pragma unroll
    for (int s = 0; s < 4; ++s){
      acc0 = __builtin_amdgcn_mfma_f32_16x16x32_bf16(af[s], bf[s][0], acc0, 0,0,0);
      acc1 = __builtin_amdgcn_mfma_f32_16x16x32_bf16(af[s], bf[s][1], acc1, 0,0,0);
    }
    #pragma unroll
    for (int r = 0; r < 4; ++r){
      int g = mb + quad*4 + r;
      float v0 = acc0[r], v1 = acc1[r];
      unsigned u0 = pk(v0, __shfl_xor(v0, 1));
      unsigned u1 = pk(v1, __shfl_xor(v1, 1));
      bool ok = g < n;
      if (((lane & 1) == 0) && ok){
        H2[(size_t)g*64 + w*16 + (m >> 1)]     = u0;
        H2[(size_t)g*64 + w*16 + 8 + (m >> 1)] = u1;
      }
      float s1 = v0*avv[0] + v1*avv[1];
      float s2 = v0*dvv[0] + v1*dvv[1];
      s1 += __shfl_xor(s1,1); s1 += __shfl_xor(s1,2); s1 += __shfl_xor(s1,4); s1 += __shfl_xor(s1,8);
      s2 += __shfl_xor(s2,1); s2 += __shfl_xor(s2,2); s2 += __shfl_xor(s2,4); s2 += __shfl_xor(s2,8);
      if (m == 0 && ok){ AL[g*4 + w] = s1; AD[g*4 + w] = s2; }
    }
  }
}

// ---------------- MFMA GEMM 128x40 + fused al (layer 3) -----------------------
__global__ __launch_bounds__(256) void gemm3_mfma(
    const unsigned* __restrict__ X2, const void* __restrict__ W,
    const void* __restrict__ Wsrc, const void* __restrict__ Wdst,
    const int* __restrict__ flagp,
    unsigned* __restrict__ H3, float* __restrict__ AL, float* __restrict__ AD,
    int n, int ntiles)
{
  __shared__ unsigned short WT[48*136];
  const int isbf = *flagp;
  const int t = threadIdx.x;
  for (int idx = t; idx < 128*64; idx += 256){
    int c = idx & 63, k = idx >> 6;
    if (c < 48){
      unsigned short v = 0;
      if (c < 40){
        if (isbf) v = ((const unsigned short*)W)[k*40 + c];
        else      v = (unsigned short)(pk(((const float*)W)[k*40 + c], 0.f) & 0xffffu);
      }
      WT[c*136 + k] = v;
    }
  }
  __syncthreads();
  const int w = t >> 6;
  const int lane = t & 63;
  const int m = lane & 15, quad = lane >> 4;

  frag8 bf[4][3];
  float avv[3], dvv[3];
  #pragma unroll
  for (int ct = 0; ct < 3; ++ct){
    int colc = ct*16 + m;
    #pragma unroll
    for (int s = 0; s < 4; ++s){
      int k0 = s*32 + quad*8;
      U4F8 v; v.u = *((const uint4*)&WT[colc*136 + k0]);
      bf[s][ct] = v.f;
    }
    avv[ct] = (colc < 40) ? ldf(Wsrc, colc, isbf) : 0.f;
    dvv[ct] = (colc < 40) ? ldf(Wdst, colc, isbf) : 0.f;
  }

  for (int tg = blockIdx.x; tg*4 < ntiles; tg += gridDim.x){
    const int tile = tg*4 + w;
    if (tile >= ntiles) continue;
    const int mb = tile*16;
    int nodeA = mb + m; if (nodeA >= n) nodeA = n - 1;
    frag8 af[4];
    #pragma unroll
    for (int s = 0; s < 4; ++s)
      af[s] = load_a_pairs(X2, nodeA, s*32 + quad*8);
    f32x4 acc[3];
    #pragma unroll
    for (int ct = 0; ct < 3; ++ct) acc[ct] = (f32x4){0.f,0.f,0.f,0.f};
    #pragma unroll
    for (int s = 0; s < 4; ++s){
      acc[0] = __builtin_amdgcn_mfma_f32_16x16x32_bf16(af[s], bf[s][0], acc[0], 0,0,0);
      acc[1] = __builtin_amdgcn_mfma_f32_16x16x32_bf16(af[s], bf[s][1], acc[1], 0,0,0);
      acc[2] = __builtin_amdgcn_mfma_f32_16x16x32_bf16(af[s], bf[s][2], acc[2], 0,0,0);
    }
    #pragma unroll
    for (int r = 0; r < 4; ++r){
      int g = mb + quad*4 + r;
      bool ok = g < n;
      float ps = 0.f, pd = 0.f;
      #pragma unroll
      for (int ct = 0; ct < 3; ++ct){
        float v = acc[ct][r];
        ps += v*avv[ct]; pd += v*dvv[ct];
        unsigned u = pk(v, __shfl_xor(v, 1));
        bool stok = ((lane & 1) == 0) && ok && (ct < 2 || m < 8);
        if (stok) H3[(size_t)g*20 + ct*8 + (m >> 1)] = u;
      }
      ps += __shfl_xor(ps,1); ps += __shfl_xor(ps,2); ps += __shfl_xor(ps,4); ps += __shfl_xor(ps,8);
      pd += __shfl_xor(pd,1); pd += __shfl_xor(pd,2); pd += __shfl_xor(pd,4); pd += __shfl_xor(pd,8);
      if (m == 0 && ok){ AL[g] = ps; AD[g] = pd; }
    }
  }
}

// ---------------- aggregation (layers 1,2): wave/node, 2 edges per instr -------
// lanes 0-31 = even edge, 32-63 = odd edge; each lane loads uint2 (4 channels).
__global__ __launch_bounds__(256) void agg4(
    const unsigned* __restrict__ H2,
    const float* __restrict__ ALf, const float* __restrict__ ADf,
    const float* __restrict__ Wp,           // fp32 weights, 4 per CSR slot
    const int* __restrict__ cnt, const int* __restrict__ start, const int* __restrict__ col,
    const void* __restrict__ bias, const void* __restrict__ bng, const void* __restrict__ bnb,
    const void* __restrict__ bnm,  const void* __restrict__ bnv,
    const int* __restrict__ flagp,
    unsigned* __restrict__ Hout, int n)
{
  const int isbf = *flagp;
  const int wave = threadIdx.x >> 6;
  const int lane = threadIdx.x & 63;
  const int node = blockIdx.x*4 + wave;
  if (node >= n) return;
  const int half = lane >> 5, sl = lane & 31;
  const int head = sl >> 3;
  const int base = start[node], deg = cnt[node];

  float l = 0.f, aLx = 0.f, aHx = 0.f, aLy = 0.f, aHy = 0.f;
  // self loop (half 0 only; halves are summed at the end)
  {
    uint2 hs = *((const uint2*)(H2 + (size_t)node*64) + sl);
    float es = (half == 0) ? __expf(lrelu(ALf[node*4+head] + ADf[node*4+head])) : 0.f;
    l = es;
    aLx = es*bflo(hs.x); aHx = es*bfhi(hs.x);
    aLy = es*bflo(hs.y); aHy = es*bfhi(hs.y);
  }

  for (int i = 0; i < deg; i += 16){
    int sv[8]; float wv[8];
    #pragma unroll
    for (int u = 0; u < 8; ++u){
      int j = i + 2*u + half;
      bool valid = j < deg;
      int jj = valid ? j : (deg - 1);
      sv[u] = valid ? col[base + jj] : node;   // masked lanes hit own (cached) row
      wv[u] = valid ? Wp[(size_t)(base + jj)*4 + head] : 0.f;
    }
    uint2 hv[8];
    #pragma unroll
    for (int u = 0; u < 8; ++u)
      hv[u] = *((const uint2*)(H2 + (size_t)sv[u]*64) + sl);
    #pragma unroll
    for (int u = 0; u < 8; ++u){
      float w = wv[u];
      l   += w;
      aLx += w * bflo(hv[u].x); aHx += w * bfhi(hv[u].x);
      aLy += w * bflo(hv[u].y); aHy += w * bfhi(hv[u].y);
    }
  }

  // combine halves
  l   += __shfl_xor(l, 32);
  aLx += __shfl_xor(aLx, 32); aHx += __shfl_xor(aHx, 32);
  aLy += __shfl_xor(aLy, 32); aHy += __shfl_xor(aHy, 32);

  if (half == 0){
    const float rl = 1.f / l;
    const int c0 = 4*sl;
    float v[4] = {aLx*rl, aHx*rl, aLy*rl, aHy*rl};
    unsigned o[2];
    #pragma unroll
    for (int q = 0; q < 2; ++q){
      float r0, r1;
      {
        int c = c0 + 2*q;
        float z = fmaxf(v[2*q] + ldf(bias,c,isbf), 0.f);
        r0 = (z - ldf(bnm,c,isbf)) * rsqrtf(ldf(bnv,c,isbf) + BN_EPS) * ldf(bng,c,isbf) + ldf(bnb,c,isbf);
      }
      {
        int c = c0 + 2*q + 1;
        float z = fmaxf(v[2*q+1] + ldf(bias,c,isbf), 0.f);
        r1 = (z - ldf(bnm,c,isbf)) * rsqrtf(ldf(bnv,c,isbf) + BN_EPS) * ldf(bng,c,isbf) + ldf(bnb,c,isbf);
      }
      o[q] = pk(r0, r1);
    }
    *((uint2*)(Hout + (size_t)node*64) + sl) = make_uint2(o[0], o[1]);
  }
}

// ---------------- aggregation (layer 3) + log_softmax -------------------------
__global__ __launch_bounds__(256) void agg1(
    const unsigned* __restrict__ H3,
    const float* __restrict__ AL, const float* __restrict__ AD,
    const float* __restrict__ W1p,
    const int* __restrict__ cnt, const int* __restrict__ start, const int* __restrict__ col,
    const void* __restrict__ b3, const int* __restrict__ flagp,
    void* __restrict__ out, int n)
{
  const int isbf = *flagp;
  const int wave = threadIdx.x >> 6;
  const int lane = threadIdx.x & 63;
  const int node = blockIdx.x*4 + wave;
  if (node >= n) return;
  const bool act = lane < 20;
  const int base = start[node], deg = cnt[node];

  float accL, accH, l;
  {
    float e = __expf(lrelu(AL[node] + AD[node]));
    unsigned h = act ? H3[(size_t)node*20 + lane] : 0u;
    l = e; accL = e * bflo(h); accH = e * bfhi(h);
  }

  for (int i = 0; i < deg; i += 8){
    int sv[8]; float wv[8]; unsigned hv[8];
    #pragma unroll
    for (int u = 0; u < 8; ++u){
      int j = i + u;
      bool valid = j < deg;
      int jj = valid ? j : (deg - 1);
      sv[u] = valid ? col[base + jj] : node;
      wv[u] = valid ? W1p[base + jj] : 0.f;
    }
    #pragma unroll
    for (int u = 0; u < 8; ++u) hv[u] = act ? H3[(size_t)sv[u]*20 + lane] : 0u;
    #pragma unroll
    for (int u = 0; u < 8; ++u){
      float w = wv[u];
      l += w; accL += w * bflo(hv[u]); accH += w * bfhi(hv[u]);
    }
  }

  const float rl = 1.f / l;
  const int c0 = 2*lane;
  float z0 = act ? (accL*rl + ldf(b3, c0,     isbf)) : NEGBIG;
  float z1 = act ? (accH*rl + ldf(b3, c0 + 1, isbf)) : NEGBIG;
  float mx = fmaxf(z0, z1);
  #pragma unroll
  for (int off = 1; off < 64; off <<= 1) mx = fmaxf(mx, __shfl_xor(mx, off));
  float p = act ? (__expf(z0 - mx) + __expf(z1 - mx)) : 0.f;
  float sum = p;
  #pragma unroll
  for (int off = 1; off < 64; off <<= 1) sum += __shfl_xor(sum, off);
  if (act){
    float lg = __logf(sum);
    float r0 = z0 - mx - lg, r1 = z1 - mx - lg;
    if (isbf) ((unsigned*)out)[(size_t)node*20 + lane] = pk(r0, r1);
    else      ((float2*)out)[(size_t)node*20 + lane] = make_float2(r0, r1);
  }
}

// ---------------- launch ----------------
extern "C" void kernel_launch(void* const* d_in, const int* in_sizes, int n_in,
                              void* d_out, int out_size, void* d_ws, size_t ws_size,
                              hipStream_t stream)
{
  (void)n_in; (void)out_size; (void)ws_size;
  const void* x    = d_in[0];
  const int*  ei   = (const int*)d_in[1];
  const void* W1   = d_in[2];
  const void* as1  = d_in[3];
  const void* ad1  = d_in[4];
  const void* b1   = d_in[5];
  const void* W2   = d_in[6];
  const void* as2  = d_in[7];
  const void* ad2  = d_in[8];
  const void* b2   = d_in[9];
  const void* W3   = d_in[10];
  const void* as3  = d_in[11];
  const void* ad3  = d_in[12];
  const void* b3   = d_in[13];
  const void* bn1g = d_in[14];
  const void* bn1b = d_in[15];
  const void* bn1m = d_in[16];
  const void* bn1v = d_in[17];
  const void* bn2g = d_in[18];
  const void* bn2b = d_in[19];
  const void* bn2m = d_in[20];
  const void* bn2v = d_in[21];

  const int N  = in_sizes[0] / 128;
  const int E  = in_sizes[1] / 2;
  const int ntiles = (N + 15) / 16;

  char* w = (char*)d_ws;
  size_t off = 0;
  auto alloc = [&](size_t bytes)->char*{
    char* p = w + off; off = (off + bytes + 255) & ~(size_t)255; return p;
  };
  unsigned* H2A = (unsigned*)alloc((size_t)N*64*4);
  unsigned* H2B = (unsigned*)alloc((size_t)N*64*4);
  unsigned* H3p = (unsigned*)alloc((size_t)N*20*4);
  float* AL    = (float*)alloc((size_t)N*4*4);
  float* AD    = (float*)alloc((size_t)N*4*4);
  int*   headp = (int*)alloc((size_t)N*4);
  int*   nextp = (int*)alloc((size_t)E*4);
  int*   cnt   = (int*)alloc((size_t)N*4);
  int*   start = (int*)alloc((size_t)N*4);
  int*   col   = (int*)alloc((size_t)E*4);
  int*   rowid = (int*)alloc((size_t)E*4);
  float* Wedge = (float*)alloc((size_t)E*4*4);   // w4 (layers 1,2); w1 aliases
  int*   flag  = (int*)alloc(256);
  int*   total = (int*)alloc(256);

  const int* srcp = ei;
  const int* dstp = ei + E;

  const int nb256 = (N + 255)/256, eb256 = (E + 255)/256;
  const int bb = (N + 3)/4;
  int g1 = ntiles < 625 ? ntiles : 625;
  int g3 = (ntiles + 3)/4; if (g3 > 400) g3 = 400;

  init_detect<<<nb256,256,0,stream>>>(headp, (const unsigned short*)W1, flag, total, N);
  chain_build<<<eb256,256,0,stream>>>(dstp, headp, nextp, E, N);
  csr_scan_walk<<<nb256,256,0,stream>>>(headp, nextp, cnt, start, total, N);
  chain_fill<<<nb256,256,0,stream>>>(headp, nextp, srcp, start, col, rowid, N);

  // layer 1
  gemm_al_mfma<<<g1,256,0,stream>>>(x, 0, W1, as1, ad1, flag, H2A, AL, AD, N, ntiles);
  wgt4<<<eb256,256,0,stream>>>(col, rowid, (const float4*)AL, (const float4*)AD,
                               (float4*)Wedge, E, N);
  agg4<<<bb,256,0,stream>>>(H2A, AL, AD, Wedge, cnt, start, col,
                            b1, bn1g, bn1b, bn1m, bn1v, flag, H2B, N);
  // layer 2
  gemm_al_mfma<<<g1,256,0,stream>>>(H2B, 1, W2, as2, ad2, flag, H2A, AL, AD, N, ntiles);
  wgt4<<<eb256,256,0,stream>>>(col, rowid, (const float4*)AL, (const float4*)AD,
                               (float4*)Wedge, E, N);
  agg4<<<bb,256,0,stream>>>(H2A, AL, AD, Wedge, cnt, start, col,
                            b2, bn2g, bn2b, bn2m, bn2v, flag, H2B, N);
  // layer 3
  gemm3_mfma<<<g3,256,0,stream>>>(H2B, W3, as3, ad3, flag, H3p, AL, AD, N, ntiles);
  wgt1<<<eb256,256,0,stream>>>(col, rowid, AL, AD, Wedge, E, N);
  agg1<<<bb,256,0,stream>>>(H3p, AL, AD, Wedge, cnt, start, col, b3, flag, d_out, N);
}

// Round 8
// 381.989 us; speedup vs baseline: 1.1309x; 1.1309x over previous
//
#include <hip/hip_runtime.h>
#include <hip/hip_bf16.h>
#include <math.h>

using bf16 = __hip_bfloat16;
using frag8 = __attribute__((ext_vector_type(8))) short;
using f32x4 = __attribute__((ext_vector_type(4))) float;

#define LEAKY 0.2f
#define BN_EPS 1e-5f
#define NEGBIG -1e30f

__device__ __forceinline__ float lrelu(float z){ return z > 0.f ? z : LEAKY * z; }
__device__ __forceinline__ float bflo(unsigned u){ return __uint_as_float(u << 16); }
__device__ __forceinline__ float bfhi(unsigned u){ return __uint_as_float(u & 0xffff0000u); }
// pack two floats into bf16 pair (RNE)
__device__ __forceinline__ unsigned pk(float a, float b){
  unsigned ua = __float_as_uint(a), ub = __float_as_uint(b);
  ua += 0x7fffu + ((ua >> 16) & 1u);
  ub += 0x7fffu + ((ub >> 16) & 1u);
  return (ua >> 16) | (ub & 0xffff0000u);
}
// dtype-adaptive load: isbf=1 -> bf16, else fp32
__device__ __forceinline__ float ldf(const void* p, size_t i, int isbf){
  if (isbf) return (float)((const bf16*)p)[i];
  return ((const float*)p)[i];
}

union U4F8 { uint4 u; frag8 f; };

__device__ __forceinline__ frag8 load_a_pairs(const unsigned* __restrict__ X2, int node, int k0){
  U4F8 v; v.u = *((const uint4*)(X2 + (size_t)node*64 + (k0 >> 1))); return v.f;
}
__device__ __forceinline__ frag8 load_a_f32(const float* __restrict__ X, int node, int k0){
  float4 q0 = *((const float4*)(X + (size_t)node*128 + k0));
  float4 q1 = *((const float4*)(X + (size_t)node*128 + k0 + 4));
  U4F8 v; v.u = make_uint4(pk(q0.x,q0.y), pk(q0.z,q0.w), pk(q1.x,q1.y), pk(q1.z,q1.w));
  return v.f;
}

// ------------- head init (-1) + total=0 + fused input-dtype detector ----------
__global__ void init_detect(int* head, const unsigned short* __restrict__ w1bits,
                            int* flag, int* total, int n){
  int g = blockIdx.x*256 + threadIdx.x;
  if (g < n) head[g] = -1;
  if (g == 0) *total = 0;
  if (blockIdx.x == 0){
    __shared__ int cntr;
    if (threadIdx.x == 0) cntr = 0;
    __syncthreads();
    unsigned u = w1bits[threadIdx.x * 2];
    int e = (u >> 7) & 0xff;
    atomicAdd(&cntr, (e >= 64 && e <= 140) ? 1 : 0);
    __syncthreads();
    if (threadIdx.x == 0) *flag = (cntr >= 160) ? 1 : 0;
  }
}

// ------------- chain build: next[e] = atomicExch(&head[dst[e]], e) ------------
__global__ void chain_build(const int* __restrict__ dst, int* head, int* next,
                            int e, int n){
  int g = blockIdx.x*256 + threadIdx.x;
  if (g < e){
    int d = dst[g];
    next[g] = ((unsigned)d < (unsigned)n) ? atomicExch(&head[d], g) : -1;
  }
}

// ------------- fused chain-walk degree count + block scan -> start ------------
__global__ void csr_scan_walk(const int* __restrict__ head, const int* __restrict__ next,
                              int* cnt, int* start, int* total, int n){
  __shared__ int s[256];
  __shared__ int base_s;
  int t = threadIdx.x;
  int g = blockIdx.x*256 + t;
  int v = 0;
  if (g < n){
    for (int e = head[g]; e != -1; e = next[e]) ++v;
    cnt[g] = v;
  }
  s[t] = v;
  __syncthreads();
  for (int off = 1; off < 256; off <<= 1){
    int x = (t >= off) ? s[t-off] : 0;
    __syncthreads();
    s[t] += x;
    __syncthreads();
  }
  if (t == 255) base_s = atomicAdd(total, s[255]);
  __syncthreads();
  if (g < n) start[g] = base_s + s[t] - v;
}

// ------------- per-node chain walk: sequential col fill (pre-clamped) ---------
__global__ void chain_fill(const int* __restrict__ head, const int* __restrict__ next,
                           const int* __restrict__ src, const int* __restrict__ start,
                           int* col, int n){
  int g = blockIdx.x*256 + threadIdx.x;
  if (g >= n) return;
  int p = start[g];
  for (int e = head[g]; e != -1; e = next[e]){
    int s = src[e];
    if ((unsigned)s >= (unsigned)n) s = 0;   // clamp once here, never per-layer
    col[p++] = s;
  }
}

// ---------------- MFMA GEMM 128x128 + fused al (layers 1,2) --------------------
__global__ __launch_bounds__(256) void gemm_al_mfma(
    const void* __restrict__ X, int xkind,
    const void* __restrict__ W, const void* __restrict__ Wsrc, const void* __restrict__ Wdst,
    const int* __restrict__ flagp,
    unsigned* __restrict__ H2, float* __restrict__ AL, float* __restrict__ AD,
    int n, int ntiles)
{
  __shared__ unsigned short WT[128*136];
  const int isbf = *flagp;
  const int t = threadIdx.x;
  if (isbf){
    const unsigned short* W16 = (const unsigned short*)W;
    for (int idx = t; idx < 16384; idx += 256){
      int k = idx >> 7, nn = idx & 127;
      WT[nn*136 + k] = W16[idx];
    }
  } else {
    const float* Wf = (const float*)W;
    for (int idx = t; idx < 16384; idx += 256){
      int k = idx >> 7, nn = idx & 127;
      WT[nn*136 + k] = (unsigned short)(pk(Wf[idx], 0.f) & 0xffffu);
    }
  }
  __syncthreads();
  const int w = t >> 6;
  const int lane = t & 63;
  const int m = lane & 15, quad = lane >> 4;

  frag8 bf[4][2];
  #pragma unroll
  for (int s = 0; s < 4; ++s)
    #pragma unroll
    for (int ct = 0; ct < 2; ++ct){
      int colc = w*32 + ct*16 + m;
      int k0 = s*32 + quad*8;
      U4F8 v; v.u = *((const uint4*)&WT[colc*136 + k0]);
      bf[s][ct] = v.f;
    }
  float avv[2], dvv[2];
  #pragma unroll
  for (int ct = 0; ct < 2; ++ct){
    int colc = w*32 + ct*16 + m;
    avv[ct] = ldf(Wsrc, colc, isbf);
    dvv[ct] = ldf(Wdst, colc, isbf);
  }
  const bool pairs = (xkind == 1) || isbf;

  for (int tile = blockIdx.x; tile < ntiles; tile += gridDim.x){
    const int mb = tile*16;
    int nodeA = mb + m; if (nodeA >= n) nodeA = n - 1;
    frag8 af[4];
    #pragma unroll
    for (int s = 0; s < 4; ++s){
      int k0 = s*32 + quad*8;
      af[s] = pairs ? load_a_pairs((const unsigned*)X, nodeA, k0)
                    : load_a_f32((const float*)X, nodeA, k0);
    }
    f32x4 acc0 = {0.f,0.f,0.f,0.f}, acc1 = {0.f,0.f,0.f,0.f};
    #pragma unroll
    for (int s = 0; s < 4; ++s){
      acc0 = __builtin_amdgcn_mfma_f32_16x16x32_bf16(af[s], bf[s][0], acc0, 0,0,0);
      acc1 = __builtin_amdgcn_mfma_f32_16x16x32_bf16(af[s], bf[s][1], acc1, 0,0,0);
    }
    #pragma unroll
    for (int r = 0; r < 4; ++r){
      int g = mb + quad*4 + r;
      float v0 = acc0[r], v1 = acc1[r];
      unsigned u0 = pk(v0, __shfl_xor(v0, 1));
      unsigned u1 = pk(v1, __shfl_xor(v1, 1));
      bool ok = g < n;
      if (((lane & 1) == 0) && ok){
        H2[(size_t)g*64 + w*16 + (m >> 1)]     = u0;
        H2[(size_t)g*64 + w*16 + 8 + (m >> 1)] = u1;
      }
      float s1 = v0*avv[0] + v1*avv[1];
      float s2 = v0*dvv[0] + v1*dvv[1];
      s1 += __shfl_xor(s1,1); s1 += __shfl_xor(s1,2); s1 += __shfl_xor(s1,4); s1 += __shfl_xor(s1,8);
      s2 += __shfl_xor(s2,1); s2 += __shfl_xor(s2,2); s2 += __shfl_xor(s2,4); s2 += __shfl_xor(s2,8);
      if (m == 0 && ok){ AL[g*4 + w] = s1; AD[g*4 + w] = s2; }
    }
  }
}

// ---------------- MFMA GEMM 128x40 + fused al (layer 3) -----------------------
__global__ __launch_bounds__(256) void gemm3_mfma(
    const unsigned* __restrict__ X2, const void* __restrict__ W,
    const void* __restrict__ Wsrc, const void* __restrict__ Wdst,
    const int* __restrict__ flagp,
    unsigned* __restrict__ H3, float* __restrict__ AL, float* __restrict__ AD,
    int n, int ntiles)
{
  __shared__ unsigned short WT[48*136];
  const int isbf = *flagp;
  const int t = threadIdx.x;
  for (int idx = t; idx < 128*64; idx += 256){
    int c = idx & 63, k = idx >> 6;
    if (c < 48){
      unsigned short v = 0;
      if (c < 40){
        if (isbf) v = ((const unsigned short*)W)[k*40 + c];
        else      v = (unsigned short)(pk(((const float*)W)[k*40 + c], 0.f) & 0xffffu);
      }
      WT[c*136 + k] = v;
    }
  }
  __syncthreads();
  const int w = t >> 6;
  const int lane = t & 63;
  const int m = lane & 15, quad = lane >> 4;

  frag8 bf[4][3];
  float avv[3], dvv[3];
  #pragma unroll
  for (int ct = 0; ct < 3; ++ct){
    int colc = ct*16 + m;
    #pragma unroll
    for (int s = 0; s < 4; ++s){
      int k0 = s*32 + quad*8;
      U4F8 v; v.u = *((const uint4*)&WT[colc*136 + k0]);
      bf[s][ct] = v.f;
    }
    avv[ct] = (colc < 40) ? ldf(Wsrc, colc, isbf) : 0.f;
    dvv[ct] = (colc < 40) ? ldf(Wdst, colc, isbf) : 0.f;
  }

  for (int tg = blockIdx.x; tg*4 < ntiles; tg += gridDim.x){
    const int tile = tg*4 + w;
    if (tile >= ntiles) continue;
    const int mb = tile*16;
    int nodeA = mb + m; if (nodeA >= n) nodeA = n - 1;
    frag8 af[4];
    #pragma unroll
    for (int s = 0; s < 4; ++s)
      af[s] = load_a_pairs(X2, nodeA, s*32 + quad*8);
    f32x4 acc[3];
    #pragma unroll
    for (int ct = 0; ct < 3; ++ct) acc[ct] = (f32x4){0.f,0.f,0.f,0.f};
    #pragma unroll
    for (int s = 0; s < 4; ++s){
      acc[0] = __builtin_amdgcn_mfma_f32_16x16x32_bf16(af[s], bf[s][0], acc[0], 0,0,0);
      acc[1] = __builtin_amdgcn_mfma_f32_16x16x32_bf16(af[s], bf[s][1], acc[1], 0,0,0);
      acc[2] = __builtin_amdgcn_mfma_f32_16x16x32_bf16(af[s], bf[s][2], acc[2], 0,0,0);
    }
    #pragma unroll
    for (int r = 0; r < 4; ++r){
      int g = mb + quad*4 + r;
      bool ok = g < n;
      float ps = 0.f, pd = 0.f;
      #pragma unroll
      for (int ct = 0; ct < 3; ++ct){
        float v = acc[ct][r];
        ps += v*avv[ct]; pd += v*dvv[ct];
        unsigned u = pk(v, __shfl_xor(v, 1));
        bool stok = ((lane & 1) == 0) && ok && (ct < 2 || m < 8);
        if (stok) H3[(size_t)g*20 + ct*8 + (m >> 1)] = u;
      }
      ps += __shfl_xor(ps,1); ps += __shfl_xor(ps,2); ps += __shfl_xor(ps,4); ps += __shfl_xor(ps,8);
      pd += __shfl_xor(pd,1); pd += __shfl_xor(pd,2); pd += __shfl_xor(pd,4); pd += __shfl_xor(pd,8);
      if (m == 0 && ok){ AL[g] = ps; AD[g] = pd; }
    }
  }
}

// ---------------- aggregation (layers 1,2): wave/node, 8-wide edge unroll ------
// (round-6 proven shape; col pre-clamped so no per-edge bounds checks)
__global__ __launch_bounds__(256) void agg4(
    const unsigned* __restrict__ H2,
    const float* __restrict__ ALf, const float* __restrict__ ADf,
    const int* __restrict__ cnt, const int* __restrict__ start, const int* __restrict__ col,
    const void* __restrict__ bias, const void* __restrict__ bng, const void* __restrict__ bnb,
    const void* __restrict__ bnm,  const void* __restrict__ bnv,
    const int* __restrict__ flagp,
    unsigned* __restrict__ Hout, int n)
{
  const int isbf = *flagp;
  const int wave = threadIdx.x >> 6;
  const int lane = threadIdx.x & 63;
  const int node = blockIdx.x*4 + wave;
  if (node >= n) return;
  const int head = lane >> 4;
  const float ad = ADf[node*4 + head];
  const int base = start[node], deg = cnt[node];

  float accL, accH, l;
  {
    float e = __expf(lrelu(ALf[node*4 + head] + ad));
    unsigned h = H2[(size_t)node*64 + lane];
    l = e; accL = e * bflo(h); accH = e * bfhi(h);
  }

  int i = 0;
  for (; i + 8 <= deg; i += 8){
    int sv[8]; float av[8]; unsigned hv[8];
    #pragma unroll
    for (int u = 0; u < 8; ++u) sv[u] = col[base + i + u];
    #pragma unroll
    for (int u = 0; u < 8; ++u) av[u] = ALf[sv[u]*4 + head];
    #pragma unroll
    for (int u = 0; u < 8; ++u) hv[u] = H2[(size_t)sv[u]*64 + lane];
    #pragma unroll
    for (int u = 0; u < 8; ++u){
      float e = __expf(lrelu(av[u] + ad));
      l    += e;
      accL += e * bflo(hv[u]);
      accH += e * bfhi(hv[u]);
    }
  }
  for (; i < deg; ++i){
    int s = col[base + i];
    float a = ALf[s*4 + head];
    unsigned h = H2[(size_t)s*64 + lane];
    float e = __expf(lrelu(a + ad));
    l += e; accL += e * bflo(h); accH += e * bfhi(h);
  }

  const float rl = 1.f / l;
  const int c0 = 2*lane, c1 = c0 + 1;
  float v0 = fmaxf(accL*rl + ldf(bias,c0,isbf), 0.f);
  v0 = (v0 - ldf(bnm,c0,isbf)) * rsqrtf(ldf(bnv,c0,isbf) + BN_EPS) * ldf(bng,c0,isbf) + ldf(bnb,c0,isbf);
  float v1 = fmaxf(accH*rl + ldf(bias,c1,isbf), 0.f);
  v1 = (v1 - ldf(bnm,c1,isbf)) * rsqrtf(ldf(bnv,c1,isbf) + BN_EPS) * ldf(bng,c1,isbf) + ldf(bnb,c1,isbf);
  Hout[(size_t)node*64 + lane] = pk(v0, v1);
}

// ---------------- aggregation (layer 3) + log_softmax -------------------------
// 3 lane-groups of 20 process 3 edges per instruction (H3 rows are 20 uints).
__global__ __launch_bounds__(256) void agg1(
    const unsigned* __restrict__ H3,
    const float* __restrict__ AL, const float* __restrict__ AD,
    const int* __restrict__ cnt, const int* __restrict__ start, const int* __restrict__ col,
    const void* __restrict__ b3, const int* __restrict__ flagp,
    void* __restrict__ out, int n)
{
  const int isbf = *flagp;
  const int wave = threadIdx.x >> 6;
  const int lane = threadIdx.x & 63;
  const int node = blockIdx.x*4 + wave;
  if (node >= n) return;
  const float ad = AD[node];
  const int grp = lane / 20;           // 0,1,2 active; 3 = idle lanes 60-63
  const int cl  = lane - grp*20;
  const bool g3 = grp < 3;
  const int base = start[node], deg = cnt[node];

  float accL = 0.f, accH = 0.f, l = 0.f;
  if (grp == 0){                        // self loop on group 0 only
    float e = __expf(lrelu(AL[node] + ad));
    unsigned h = H3[(size_t)node*20 + cl];
    l = e; accL = e * bflo(h); accH = e * bfhi(h);
  }

  for (int i = 0; i < deg; i += 3){
    int j = i + grp;
    bool valid = g3 && (j < deg);
    int jj = valid ? j : (deg - 1);
    int s  = valid ? col[base + jj] : node;
    float a = AL[s];
    unsigned h = H3[(size_t)s*20 + cl];
    float e = valid ? __expf(lrelu(a + ad)) : 0.f;
    l += e; accL += e * bflo(h); accH += e * bfhi(h);
  }

  // combine the 3 groups (partners at lane+20, lane+40)
  int p1 = (lane + 20) & 63, p2 = (lane + 40) & 63;
  l    += __shfl(l, p1)    + __shfl(l, p2);
  accL += __shfl(accL, p1) + __shfl(accL, p2);
  accH += __shfl(accH, p1) + __shfl(accH, p2);

  const bool act = lane < 20;
  const float rl = 1.f / l;
  const int c0 = 2*lane;
  float z0 = act ? (accL*rl + ldf(b3, c0,     isbf)) : NEGBIG;
  float z1 = act ? (accH*rl + ldf(b3, c0 + 1, isbf)) : NEGBIG;
  float mx = fmaxf(z0, z1);
  #pragma unroll
  for (int off = 1; off < 64; off <<= 1) mx = fmaxf(mx, __shfl_xor(mx, off));
  float p = act ? (__expf(z0 - mx) + __expf(z1 - mx)) : 0.f;
  float sum = p;
  #pragma unroll
  for (int off = 1; off < 64; off <<= 1) sum += __shfl_xor(sum, off);
  if (act){
    float lg = __logf(sum);
    float r0 = z0 - mx - lg, r1 = z1 - mx - lg;
    if (isbf) ((unsigned*)out)[(size_t)node*20 + lane] = pk(r0, r1);
    else      ((float2*)out)[(size_t)node*20 + lane] = make_float2(r0, r1);
  }
}

// ---------------- launch ----------------
extern "C" void kernel_launch(void* const* d_in, const int* in_sizes, int n_in,
                              void* d_out, int out_size, void* d_ws, size_t ws_size,
                              hipStream_t stream)
{
  (void)n_in; (void)out_size; (void)ws_size;
  const void* x    = d_in[0];
  const int*  ei   = (const int*)d_in[1];
  const void* W1   = d_in[2];
  const void* as1  = d_in[3];
  const void* ad1  = d_in[4];
  const void* b1   = d_in[5];
  const void* W2   = d_in[6];
  const void* as2  = d_in[7];
  const void* ad2  = d_in[8];
  const void* b2   = d_in[9];
  const void* W3   = d_in[10];
  const void* as3  = d_in[11];
  const void* ad3  = d_in[12];
  const void* b3   = d_in[13];
  const void* bn1g = d_in[14];
  const void* bn1b = d_in[15];
  const void* bn1m = d_in[16];
  const void* bn1v = d_in[17];
  const void* bn2g = d_in[18];
  const void* bn2b = d_in[19];
  const void* bn2m = d_in[20];
  const void* bn2v = d_in[21];

  const int N  = in_sizes[0] / 128;
  const int E  = in_sizes[1] / 2;
  const int ntiles = (N + 15) / 16;

  char* w = (char*)d_ws;
  size_t off = 0;
  auto alloc = [&](size_t bytes)->char*{
    char* p = w + off; off = (off + bytes + 255) & ~(size_t)255; return p;
  };
  unsigned* H2A = (unsigned*)alloc((size_t)N*64*4);
  unsigned* H2B = (unsigned*)alloc((size_t)N*64*4);
  unsigned* H3p = (unsigned*)alloc((size_t)N*20*4);
  float* AL    = (float*)alloc((size_t)N*4*4);
  float* AD    = (float*)alloc((size_t)N*4*4);
  int*   headp = (int*)alloc((size_t)N*4);
  int*   nextp = (int*)alloc((size_t)E*4);
  int*   cnt   = (int*)alloc((size_t)N*4);
  int*   start = (int*)alloc((size_t)N*4);
  int*   col   = (int*)alloc((size_t)E*4);
  int*   flag  = (int*)alloc(256);
  int*   total = (int*)alloc(256);

  const int* srcp = ei;
  const int* dstp = ei + E;

  const int nb256 = (N + 255)/256, eb256 = (E + 255)/256;
  const int bb = (N + 3)/4;
  int g1 = ntiles < 625 ? ntiles : 625;
  int g3 = (ntiles + 3)/4; if (g3 > 400) g3 = 400;

  init_detect<<<nb256,256,0,stream>>>(headp, (const unsigned short*)W1, flag, total, N);
  chain_build<<<eb256,256,0,stream>>>(dstp, headp, nextp, E, N);
  csr_scan_walk<<<nb256,256,0,stream>>>(headp, nextp, cnt, start, total, N);
  chain_fill<<<nb256,256,0,stream>>>(headp, nextp, srcp, start, col, N);

  // layer 1
  gemm_al_mfma<<<g1,256,0,stream>>>(x, 0, W1, as1, ad1, flag, H2A, AL, AD, N, ntiles);
  agg4<<<bb,256,0,stream>>>(H2A, AL, AD, cnt, start, col,
                            b1, bn1g, bn1b, bn1m, bn1v, flag, H2B, N);
  // layer 2
  gemm_al_mfma<<<g1,256,0,stream>>>(H2B, 1, W2, as2, ad2, flag, H2A, AL, AD, N, ntiles);
  agg4<<<bb,256,0,stream>>>(H2A, AL, AD, cnt, start, col,
                            b2, bn2g, bn2b, bn2m, bn2v, flag, H2B, N);
  // layer 3
  gemm3_mfma<<<g3,256,0,stream>>>(H2B, W3, as3, ad3, flag, H3p, AL, AD, N, ntiles);
  agg1<<<bb,256,0,stream>>>(H3p, AL, AD, cnt, start, col, b3, flag, d_out, N);
}